// Round 16
// baseline (219.904 us; speedup 1.0000x reference)
//
#include <hip/hip_runtime.h>
#include <math.h>

// TopK router: logits = x @ W^T + bias; top-2; softmax over the 2; scatter.
// x: [N=16384, H=4096] fp32, W: [E=64, H=4096] fp32, bias: [64] fp32.
// d_out: [N*64] final (fp32) then [N*2] selected_experts written as floats.
//
// Round 16: rounds 5/10/12/15 (four different structures) all hit 92-96us
// with every pipe idle (MfmaUtil 12%, VALU 12.5%, HBM ~1TB/s, FETCH 142MB
// -- L3 absorbs ~45% of X). Shared invariant: 8 waves/CU (2/SIMD). The
// kernel is latency-bound and fixed-TLP; per-wave stalls are exposed with
// only one sibling wave per SIMD. Fix: 16 waves/CU. BLOCK=256 (4 waves =
// 4 K-quarters), 16 rows/block (1 A-frag/wave), grid 1024 = 4 blocks/CU
// (launch_bounds(256,4) caps VGPR at 128; per-wave state ~120). W per-lane
// from pre-split L2-resident planes straight into MFMAs (round-5/6 proven
// path, no LDS in loop -- sunk-load chains are covered by 3 sibling
// waves). X prefetched 2 chunks ahead (named A/B regs, split-before-load).
// One barrier total (before partial reduce). Numerics byte-identical:
// 3-term split, PROD6 order, ordered 4-way kq tree.

constexpr int E_EXPERTS = 64;
constexpr int H_DIM = 4096;
constexpr int BLOCK = 256;    // 4 waves = 4 kq-slices
constexpr int ROWS_B = 16;    // rows per block (one A-frag)
constexpr int KSLICE = 1024;  // k per kq slice
constexpr int NCH = 32;       // 32-k chunks per slice
constexpr int W_ELEMS = E_EXPERTS * H_DIM;

typedef __attribute__((ext_vector_type(8))) short short8;
typedef __attribute__((ext_vector_type(4))) float f32x4;

__device__ __forceinline__ float4 ld4(const float* p) {
  return *reinterpret_cast<const float4*>(p);
}
__device__ __forceinline__ short8 lds8(const unsigned short* p) {
  return *reinterpret_cast<const short8*>(p);
}

__device__ __forceinline__ unsigned short bf_rne(float x) {
  unsigned u = __builtin_bit_cast(unsigned, x);
  return (unsigned short)((u + 0x7fffu + ((u >> 16) & 1u)) >> 16);
}
__device__ __forceinline__ float bf2f(unsigned short b) {
  return __builtin_bit_cast(float, ((unsigned)b) << 16);
}
// x = h + m + l + err, |err| <= 2^-25 |x|. (h,m trunc; l RNE; residuals exact)
__device__ __forceinline__ void split3(float x, unsigned short& h,
                                       unsigned short& m, unsigned short& l) {
  unsigned short hb = (unsigned short)(__builtin_bit_cast(unsigned, x) >> 16);
  float r1 = x - bf2f(hb);
  unsigned short mb = (unsigned short)(__builtin_bit_cast(unsigned, r1) >> 16);
  float r2 = r1 - bf2f(mb);
  h = hb;
  m = mb;
  l = bf_rne(r2);
}
__device__ __forceinline__ void split3_8(float4 a, float4 b, short8& h,
                                         short8& m, short8& l) {
  unsigned short hh, mm, ll;
  split3(a.x, hh, mm, ll); h[0] = (short)hh; m[0] = (short)mm; l[0] = (short)ll;
  split3(a.y, hh, mm, ll); h[1] = (short)hh; m[1] = (short)mm; l[1] = (short)ll;
  split3(a.z, hh, mm, ll); h[2] = (short)hh; m[2] = (short)mm; l[2] = (short)ll;
  split3(a.w, hh, mm, ll); h[3] = (short)hh; m[3] = (short)mm; l[3] = (short)ll;
  split3(b.x, hh, mm, ll); h[4] = (short)hh; m[4] = (short)mm; l[4] = (short)ll;
  split3(b.y, hh, mm, ll); h[5] = (short)hh; m[5] = (short)mm; l[5] = (short)ll;
  split3(b.z, hh, mm, ll); h[6] = (short)hh; m[6] = (short)mm; l[6] = (short)ll;
  split3(b.w, hh, mm, ll); h[7] = (short)hh; m[7] = (short)mm; l[7] = (short)ll;
}

// Pre-kernel: split W into h/m/l bf16 planes (same math as split3).
__global__ __launch_bounds__(256) void split_w_kernel(
    const float* __restrict__ w, unsigned short* __restrict__ wh,
    unsigned short* __restrict__ wm, unsigned short* __restrict__ wl) {
  const int i = (blockIdx.x * 256 + threadIdx.x) * 4;
  float4 v = ld4(w + i);
  ushort4 h4, m4, l4;
  split3(v.x, h4.x, m4.x, l4.x);
  split3(v.y, h4.y, m4.y, l4.y);
  split3(v.z, h4.z, m4.z, l4.z);
  split3(v.w, h4.w, m4.w, l4.w);
  *reinterpret_cast<ushort4*>(wh + i) = h4;
  *reinterpret_cast<ushort4*>(wm + i) = m4;
  *reinterpret_cast<ushort4*>(wl + i) = l4;
}

__global__ __launch_bounds__(BLOCK, 4) void topk_router_mfma(
    const float* __restrict__ x, const unsigned short* __restrict__ wh,
    const unsigned short* __restrict__ wm,
    const unsigned short* __restrict__ wl, const float* __restrict__ bias,
    float* __restrict__ out_final, float* __restrict__ out_idx) {
  __shared__ float part[4 * ROWS_B * 68];  // 17408 B, final reduce only

  const int tid = threadIdx.x;
  const int lane = tid & 63;
  const int kq = tid >> 6;  // wave = K slice (1024 k)
  const int rowBase = blockIdx.x * ROWS_B;
  const int lr = lane & 15;
  const int kg = lane >> 4;

  // Per-lane W bases: B-frag row = expert eg*16+lr, k-base kq*1024+kg*8.
  const size_t wo = (size_t)lr * H_DIM + kq * KSLICE + kg * 8;
  const unsigned short* __restrict__ whp = wh + wo;
  const unsigned short* __restrict__ wmp = wm + wo;
  const unsigned short* __restrict__ wlp = wl + wo;

  // X: this wave's 16 rows (1 A-frag) x its 1024-k slice.
  const float* __restrict__ xr =
      x + (size_t)(rowBase + lr) * H_DIM + kq * KSLICE + kg * 8;

  float4 xA0, xA1, xB0, xB1;
#define XLOADA(t)                         \
  do {                                    \
    xA0 = ld4(xr + (size_t)(t) * 32);     \
    xA1 = ld4(xr + (size_t)(t) * 32 + 4); \
  } while (0)
#define XLOADB(t)                         \
  do {                                    \
    xB0 = ld4(xr + (size_t)(t) * 32);     \
    xB1 = ld4(xr + (size_t)(t) * 32 + 4); \
  } while (0)

  f32x4 acc0 = {0.f, 0.f, 0.f, 0.f}, acc1 = acc0, acc2 = acc0, acc3 = acc0;

#define MM(d, a, b) d = __builtin_amdgcn_mfma_f32_16x16x32_bf16(a, b, d, 0, 0, 0)
#define PROD6(d, Ah, Am, Al, Bh, Bm, Bl)                      \
  MM(d, Ah, Bh); MM(d, Ah, Bm); MM(d, Am, Bh); MM(d, Am, Bm); \
  MM(d, Ah, Bl); MM(d, Al, Bh)

// One 32-k chunk: 12 per-lane W loads (L2), X split, 24 MFMAs.
#define CHUNK(c, X0, X1)                                           \
  do {                                                             \
    const size_t o_ = (size_t)(c) * 32;                            \
    short8 b0h = lds8(whp + o_);                                   \
    short8 b1h = lds8(whp + o_ + (size_t)16 * H_DIM);              \
    short8 b2h = lds8(whp + o_ + (size_t)32 * H_DIM);              \
    short8 b3h = lds8(whp + o_ + (size_t)48 * H_DIM);              \
    short8 b0m = lds8(wmp + o_);                                   \
    short8 b1m = lds8(wmp + o_ + (size_t)16 * H_DIM);              \
    short8 b2m = lds8(wmp + o_ + (size_t)32 * H_DIM);              \
    short8 b3m = lds8(wmp + o_ + (size_t)48 * H_DIM);              \
    short8 b0l = lds8(wlp + o_);                                   \
    short8 b1l = lds8(wlp + o_ + (size_t)16 * H_DIM);              \
    short8 b2l = lds8(wlp + o_ + (size_t)32 * H_DIM);              \
    short8 b3l = lds8(wlp + o_ + (size_t)48 * H_DIM);              \
    short8 ah, am, al;                                             \
    split3_8(X0, X1, ah, am, al);                                  \
    PROD6(acc0, ah, am, al, b0h, b0m, b0l);                        \
    PROD6(acc1, ah, am, al, b1h, b1m, b1l);                        \
    PROD6(acc2, ah, am, al, b2h, b2m, b2l);                        \
    PROD6(acc3, ah, am, al, b3h, b3m, b3l);                        \
  } while (0)

  // Prologue: X chunks 0,1 in flight.
  XLOADA(0);
  XLOADB(1);

  for (int c = 0; c < NCH; c += 2) {
    {
      // consume xA for chunk c; prefetch xA for c+2 AFTER the split.
      const size_t o_ = (size_t)c * 32;
      short8 b0h = lds8(whp + o_);
      short8 b1h = lds8(whp + o_ + (size_t)16 * H_DIM);
      short8 b2h = lds8(whp + o_ + (size_t)32 * H_DIM);
      short8 b3h = lds8(whp + o_ + (size_t)48 * H_DIM);
      short8 b0m = lds8(wmp + o_);
      short8 b1m = lds8(wmp + o_ + (size_t)16 * H_DIM);
      short8 b2m = lds8(wmp + o_ + (size_t)32 * H_DIM);
      short8 b3m = lds8(wmp + o_ + (size_t)48 * H_DIM);
      short8 b0l = lds8(wlp + o_);
      short8 b1l = lds8(wlp + o_ + (size_t)16 * H_DIM);
      short8 b2l = lds8(wlp + o_ + (size_t)32 * H_DIM);
      short8 b3l = lds8(wlp + o_ + (size_t)48 * H_DIM);
      short8 ah, am, al;
      split3_8(xA0, xA1, ah, am, al);
      if (c + 2 < NCH) XLOADA(c + 2);
      PROD6(acc0, ah, am, al, b0h, b0m, b0l);
      PROD6(acc1, ah, am, al, b1h, b1m, b1l);
      PROD6(acc2, ah, am, al, b2h, b2m, b2l);
      PROD6(acc3, ah, am, al, b3h, b3m, b3l);
    }
    {
      const size_t o_ = (size_t)(c + 1) * 32;
      short8 b0h = lds8(whp + o_);
      short8 b1h = lds8(whp + o_ + (size_t)16 * H_DIM);
      short8 b2h = lds8(whp + o_ + (size_t)32 * H_DIM);
      short8 b3h = lds8(whp + o_ + (size_t)48 * H_DIM);
      short8 b0m = lds8(wmp + o_);
      short8 b1m = lds8(wmp + o_ + (size_t)16 * H_DIM);
      short8 b2m = lds8(wmp + o_ + (size_t)32 * H_DIM);
      short8 b3m = lds8(wmp + o_ + (size_t)48 * H_DIM);
      short8 b0l = lds8(wlp + o_);
      short8 b1l = lds8(wlp + o_ + (size_t)16 * H_DIM);
      short8 b2l = lds8(wlp + o_ + (size_t)32 * H_DIM);
      short8 b3l = lds8(wlp + o_ + (size_t)48 * H_DIM);
      short8 ah, am, al;
      split3_8(xB0, xB1, ah, am, al);
      if (c + 3 < NCH) XLOADB(c + 3);
      PROD6(acc0, ah, am, al, b0h, b0m, b0l);
      PROD6(acc1, ah, am, al, b1h, b1m, b1l);
      PROD6(acc2, ah, am, al, b2h, b2m, b2l);
      PROD6(acc3, ah, am, al, b3h, b3m, b3l);
    }
  }

  // Partials: part[kq][row][e], row pad 68 floats.
  const int pr = kg * 4;
#define PSTORE(A, g)                                          \
  part[(size_t)(kq * 16 + pr + 0) * 68 + (g)*16 + lr] = A[0]; \
  part[(size_t)(kq * 16 + pr + 1) * 68 + (g)*16 + lr] = A[1]; \
  part[(size_t)(kq * 16 + pr + 2) * 68 + (g)*16 + lr] = A[2]; \
  part[(size_t)(kq * 16 + pr + 3) * 68 + (g)*16 + lr] = A[3];
  PSTORE(acc0, 0)
  PSTORE(acc1, 1)
  PSTORE(acc2, 2)
  PSTORE(acc3, 3)
  __syncthreads();  // the only block-wide barrier

  // Epilogue: 16 threads/row, 4 experts each; ordered 4-way kq sum,
  // stable top-2 scan, shfl_xor merge (d=1,2,4,8), softmax, scatter.
  const int r = tid >> 4;          // row 0..15
  const int te = tid & 15;
  const int eb = te * 4;
  const int n = rowBase + r;

  float v4[4];
#pragma unroll
  for (int j = 0; j < 4; ++j) {
    int e = eb + j;
    v4[j] = ((part[(size_t)(0 * 16 + r) * 68 + e] +
              part[(size_t)(1 * 16 + r) * 68 + e]) +
             (part[(size_t)(2 * 16 + r) * 68 + e] +
              part[(size_t)(3 * 16 + r) * 68 + e])) +
            bias[e];
  }

  float av = -INFINITY, bv = -INFINITY;
  int ai = E_EXPERTS, bi = E_EXPERTS;
#pragma unroll
  for (int j = 0; j < 4; ++j) {
    int e = eb + j;
    float v = v4[j];
    bool beats_a = (v > av) || (v == av && e < ai);
    bool beats_b = (v > bv) || (v == bv && e < bi);
    if (beats_a) {
      bv = av; bi = ai; av = v; ai = e;
    } else if (beats_b) {
      bv = v; bi = e;
    }
  }
#pragma unroll
  for (int d = 1; d < 16; d <<= 1) {
    float av2 = __shfl_xor(av, d);
    float bv2 = __shfl_xor(bv, d);
    int ai2 = __shfl_xor(ai, d);
    int bi2 = __shfl_xor(bi, d);
    bool afirst = (av > av2) || (av == av2 && ai < ai2);
    float na, nb;
    int nai, nbi;
    if (afirst) {
      na = av; nai = ai;
      bool t = (bv > av2) || (bv == av2 && bi < ai2);
      nb = t ? bv : av2;
      nbi = t ? bi : ai2;
    } else {
      na = av2; nai = ai2;
      bool t = (av > bv2) || (av == bv2 && ai < bi2);
      nb = t ? av : bv2;
      nbi = t ? ai : bi2;
    }
    av = na; ai = nai; bv = nb; bi = nbi;
  }

  float e1 = expf(bv - av);
  float denom = 1.0f + e1;
  float p0 = 1.0f / denom;
  float p1 = e1 / denom;

  {
    float4 o4;
    float* po = &o4.x;
#pragma unroll
    for (int j = 0; j < 4; ++j) {
      int e = eb + j;
      po[j] = (e == ai) ? p0 : (e == bi) ? p1 : 0.0f;
    }
    *reinterpret_cast<float4*>(&out_final[(size_t)n * E_EXPERTS + eb]) = o4;
  }
  if (te == 0) {
    out_idx[(size_t)n * 2 + 0] = (float)ai;
    out_idx[(size_t)n * 2 + 1] = (float)bi;
  }
}

extern "C" void kernel_launch(void* const* d_in, const int* in_sizes, int n_in,
                              void* d_out, int out_size, void* d_ws,
                              size_t ws_size, hipStream_t stream) {
  const float* x = (const float*)d_in[0];
  const float* w = (const float*)d_in[1];
  const float* bias = (const float*)d_in[2];
  const int N = in_sizes[0] / H_DIM;  // 16384
  float* out_final = (float*)d_out;
  float* out_idx = out_final + (size_t)N * E_EXPERTS;

  unsigned short* wh = (unsigned short*)d_ws;  // 3 planes x 512 KB
  unsigned short* wm = wh + W_ELEMS;
  unsigned short* wl = wm + W_ELEMS;

  split_w_kernel<<<W_ELEMS / (256 * 4), 256, 0, stream>>>(w, wh, wm, wl);
  topk_router_mfma<<<N / ROWS_B, BLOCK, 0, stream>>>(x, wh, wm, wl, bias,
                                                     out_final, out_idx);
}

// Round 17
// 93.528 us; speedup vs baseline: 2.3512x; 2.3512x over previous
//
#include <hip/hip_runtime.h>
#include <math.h>

// TopK router: logits = x @ W^T + bias; top-2; softmax over the 2; scatter.
// x: [N=16384, H=4096] fp32, W: [E=64, H=4096] fp32, bias: [64] fp32.
// d_out: [N*64] final (fp32) then [N*2] selected_experts written as floats.
//
// Round 17: NO barriers in the K loop via WAVE-PRIVATE W tiles.
// Evidence: (a) every W-in-registers variant collapsed in regalloc
// (rounds 2/3/6/14/16: VGPR 52-112, serialized loads) -> W must flow
// through LDS; (b) per-barrier fixed cost ~1650cyc (round13 vs round12
// phase scaling) -> 32 barriers = 22us, and barriers lockstep all waves
// so pipe demands serialize. Design: 8 waves = 8 K-slices (512k), all
// waves share the block's 64 rows (4 A-frags each); each wave dbufs its
// own 8KB tile (h+m planes, fragment-major 1KB regions) via 8
// global_load_lds per 32k chunk, synced ONLY by its own vmcnt (exact
// counts 28/20/0, sched_barrier-fenced). l-plane = 4 per-lane reg loads
// per chunk (consumed only by the 2 tail products per acc, issued a
// chunk early). X prefetched 2 chunks ahead (A/B reg sets). 2 barriers
// total (around the 8-way partial reduce; 139KB part aliases stage LDS).
// Numerics: 3-term split, PROD6 order per acc; 8-way kq tree (~1e-6).

constexpr int E_EXPERTS = 64;
constexpr int H_DIM = 4096;
constexpr int BLOCK = 512;   // 8 waves = 8 K-slices
constexpr int ROWS_B = 64;   // rows per block (shared by all waves)
constexpr int KSLICE = 512;  // k per wave
constexpr int NCH = 16;      // 32-k chunks per slice
constexpr int W_ELEMS = E_EXPERTS * H_DIM;
constexpr int TILE_SH = 8 * 512;      // 8 regions x 1KB = 4096 shorts
constexpr int WAVE_SH = 2 * TILE_SH;  // dbuf per wave (16 KB)

typedef __attribute__((ext_vector_type(8))) short short8;
typedef __attribute__((ext_vector_type(4))) float f32x4;

__device__ __forceinline__ float4 ld4(const float* p) {
  return *reinterpret_cast<const float4*>(p);
}
__device__ __forceinline__ short8 lds8(const unsigned short* p) {
  return *reinterpret_cast<const short8*>(p);
}
__device__ __forceinline__ void gload16(const unsigned short* g,
                                        unsigned short* l) {
  __builtin_amdgcn_global_load_lds(
      (const __attribute__((address_space(1))) void*)g,
      (__attribute__((address_space(3))) void*)l, 16, 0, 0);
}

__device__ __forceinline__ unsigned short bf_rne(float x) {
  unsigned u = __builtin_bit_cast(unsigned, x);
  return (unsigned short)((u + 0x7fffu + ((u >> 16) & 1u)) >> 16);
}
__device__ __forceinline__ float bf2f(unsigned short b) {
  return __builtin_bit_cast(float, ((unsigned)b) << 16);
}
// x = h + m + l + err, |err| <= 2^-25 |x|. (h,m trunc; l RNE; residuals exact)
__device__ __forceinline__ void split3(float x, unsigned short& h,
                                       unsigned short& m, unsigned short& l) {
  unsigned short hb = (unsigned short)(__builtin_bit_cast(unsigned, x) >> 16);
  float r1 = x - bf2f(hb);
  unsigned short mb = (unsigned short)(__builtin_bit_cast(unsigned, r1) >> 16);
  float r2 = r1 - bf2f(mb);
  h = hb;
  m = mb;
  l = bf_rne(r2);
}
__device__ __forceinline__ void split3_8(float4 a, float4 b, short8& h,
                                         short8& m, short8& l) {
  unsigned short hh, mm, ll;
  split3(a.x, hh, mm, ll); h[0] = (short)hh; m[0] = (short)mm; l[0] = (short)ll;
  split3(a.y, hh, mm, ll); h[1] = (short)hh; m[1] = (short)mm; l[1] = (short)ll;
  split3(a.z, hh, mm, ll); h[2] = (short)hh; m[2] = (short)mm; l[2] = (short)ll;
  split3(a.w, hh, mm, ll); h[3] = (short)hh; m[3] = (short)mm; l[3] = (short)ll;
  split3(b.x, hh, mm, ll); h[4] = (short)hh; m[4] = (short)mm; l[4] = (short)ll;
  split3(b.y, hh, mm, ll); h[5] = (short)hh; m[5] = (short)mm; l[5] = (short)ll;
  split3(b.z, hh, mm, ll); h[6] = (short)hh; m[6] = (short)mm; l[6] = (short)ll;
  split3(b.w, hh, mm, ll); h[7] = (short)hh; m[7] = (short)mm; l[7] = (short)ll;
}

// Pre-kernel: split W into h/m/l bf16 planes (contiguous in d_ws).
__global__ __launch_bounds__(256) void split_w_kernel(
    const float* __restrict__ w, unsigned short* __restrict__ wh,
    unsigned short* __restrict__ wm, unsigned short* __restrict__ wl) {
  const int i = (blockIdx.x * 256 + threadIdx.x) * 4;
  float4 v = ld4(w + i);
  ushort4 h4, m4, l4;
  split3(v.x, h4.x, m4.x, l4.x);
  split3(v.y, h4.y, m4.y, l4.y);
  split3(v.z, h4.z, m4.z, l4.z);
  split3(v.w, h4.w, m4.w, l4.w);
  *reinterpret_cast<ushort4*>(wh + i) = h4;
  *reinterpret_cast<ushort4*>(wm + i) = m4;
  *reinterpret_cast<ushort4*>(wl + i) = l4;
}

__global__ __launch_bounds__(BLOCK, 2) void topk_router_mfma(
    const float* __restrict__ x, const unsigned short* __restrict__ wplanes,
    const float* __restrict__ bias, float* __restrict__ out_final,
    float* __restrict__ out_idx) {
  // 139264 B: stage area (8 waves x 16KB = 131072) + aliased fp32 partials.
  __shared__ f32x4 smem4[8704];
  unsigned short* sbase = reinterpret_cast<unsigned short*>(smem4);
  float* part = reinterpret_cast<float*>(smem4);

  const int tid = threadIdx.x;
  const int lane = tid & 63;
  const int kq = tid >> 6;  // wave = K slice (512 k)
  const int rowBase = blockIdx.x * ROWS_B;
  const int lr = lane & 15;
  const int kg = lane >> 4;

  unsigned short* lb = sbase + kq * WAVE_SH;  // wave-private dbuf

  // W bases. Region (ef, pl in {h=0,m=1}) index = ef*2+pl; lane ll holds
  // W_pl[ef*16 + (ll&15)][kq*512 + t*32 + (ll>>4)*8 ..+8) at slot ll*16B.
  const unsigned short* __restrict__ wb =
      wplanes + (size_t)lr * H_DIM + kq * KSLICE + kg * 8;
  const unsigned short* __restrict__ wlb = wb + (size_t)2 * W_ELEMS;  // l

#define STAGE(t, buf)                                                       \
  do {                                                                      \
    const size_t o_ = (size_t)(t) * 32;                                     \
    unsigned short* d_ = lb + (buf)*TILE_SH;                                \
    gload16(wb + o_, d_ + 0 * 512);                                         \
    gload16(wb + o_ + (size_t)W_ELEMS, d_ + 1 * 512);                       \
    gload16(wb + o_ + (size_t)16 * H_DIM, d_ + 2 * 512);                    \
    gload16(wb + o_ + (size_t)16 * H_DIM + (size_t)W_ELEMS, d_ + 3 * 512);  \
    gload16(wb + o_ + (size_t)32 * H_DIM, d_ + 4 * 512);                    \
    gload16(wb + o_ + (size_t)32 * H_DIM + (size_t)W_ELEMS, d_ + 5 * 512);  \
    gload16(wb + o_ + (size_t)48 * H_DIM, d_ + 6 * 512);                    \
    gload16(wb + o_ + (size_t)48 * H_DIM + (size_t)W_ELEMS, d_ + 7 * 512);  \
  } while (0)

  // X: the block's 64 rows = 4 A-frags per wave, this wave's 512-k slice.
  const float* __restrict__ xr0 =
      x + (size_t)(rowBase + lr) * H_DIM + kq * KSLICE + kg * 8;
  const float* __restrict__ xr1 = xr0 + (size_t)16 * H_DIM;
  const float* __restrict__ xr2 = xr0 + (size_t)32 * H_DIM;
  const float* __restrict__ xr3 = xr0 + (size_t)48 * H_DIM;

  float4 xA00, xA01, xA10, xA11, xA20, xA21, xA30, xA31;
  float4 xB00, xB01, xB10, xB11, xB20, xB21, xB30, xB31;
#define XLOADA(t)                                                         \
  do {                                                                    \
    xA00 = ld4(xr0 + (size_t)(t) * 32); xA01 = ld4(xr0 + (size_t)(t) * 32 + 4); \
    xA10 = ld4(xr1 + (size_t)(t) * 32); xA11 = ld4(xr1 + (size_t)(t) * 32 + 4); \
    xA20 = ld4(xr2 + (size_t)(t) * 32); xA21 = ld4(xr2 + (size_t)(t) * 32 + 4); \
    xA30 = ld4(xr3 + (size_t)(t) * 32); xA31 = ld4(xr3 + (size_t)(t) * 32 + 4); \
  } while (0)
#define XLOADB(t)                                                         \
  do {                                                                    \
    xB00 = ld4(xr0 + (size_t)(t) * 32); xB01 = ld4(xr0 + (size_t)(t) * 32 + 4); \
    xB10 = ld4(xr1 + (size_t)(t) * 32); xB11 = ld4(xr1 + (size_t)(t) * 32 + 4); \
    xB20 = ld4(xr2 + (size_t)(t) * 32); xB21 = ld4(xr2 + (size_t)(t) * 32 + 4); \
    xB30 = ld4(xr3 + (size_t)(t) * 32); xB31 = ld4(xr3 + (size_t)(t) * 32 + 4); \
  } while (0)

  f32x4 c00 = {0.f, 0.f, 0.f, 0.f}, c01 = c00, c02 = c00, c03 = c00,
        c10 = c00, c11 = c00, c12 = c00, c13 = c00, c20 = c00, c21 = c00,
        c22 = c00, c23 = c00, c30 = c00, c31 = c00, c32 = c00, c33 = c00;

#define MM(d, a, b) d = __builtin_amdgcn_mfma_f32_16x16x32_bf16(a, b, d, 0, 0, 0)
#define PROD6(d, Ah, Am, Al, Bh, Bm, Bl)                      \
  MM(d, Ah, Bh); MM(d, Ah, Bm); MM(d, Am, Bh); MM(d, Am, Bm); \
  MM(d, Ah, Bl); MM(d, Al, Bh)

  // Prologue: stage chunk 0 -> buf0; X chunks 0,1 in flight. No waits.
  STAGE(0, 0);
  XLOADA(0);
  XLOADB(1);

  // Per-wave chunk body. vmcnt counts (sched_barrier-fenced issue order):
  // c==0: newer than STAGE(0) = XA(0)8 + XB(1)8 + STAGE(1)8 + WL(0)4 = 28.
  // 1<=c<=14: newer than STAGE(c) = X(c+1)8 + STAGE(c+1)8 + WL(c)4 = 20.
  // c==15: drain (no stage/X issued after) = 0.
#define BODY(c, X00, X01, X10, X11, X20, X21, X30, X31, XLOADM)              \
  do {                                                                       \
    if ((c) + 1 < NCH) STAGE((c) + 1, ((c) + 1) & 1);                        \
    const size_t wo_ = (size_t)(c) * 32;                                     \
    short8 bl0 = lds8(wlb + wo_);                                            \
    short8 bl1 = lds8(wlb + wo_ + (size_t)16 * H_DIM);                       \
    short8 bl2 = lds8(wlb + wo_ + (size_t)32 * H_DIM);                       \
    short8 bl3 = lds8(wlb + wo_ + (size_t)48 * H_DIM);                       \
    __builtin_amdgcn_sched_barrier(0);                                       \
    if ((c) == 0) {                                                          \
      asm volatile("s_waitcnt vmcnt(28)" ::: "memory");                      \
    } else if ((c) <= 14) {                                                  \
      asm volatile("s_waitcnt vmcnt(20)" ::: "memory");                      \
    } else {                                                                 \
      asm volatile("s_waitcnt vmcnt(0)" ::: "memory");                       \
    }                                                                        \
    __builtin_amdgcn_sched_barrier(0);                                       \
    const unsigned short* tb_ = lb + ((c)&1) * TILE_SH;                      \
    short8 b0h = lds8(tb_ + 0 * 512 + lane * 8);                             \
    short8 b0m = lds8(tb_ + 1 * 512 + lane * 8);                             \
    short8 b1h = lds8(tb_ + 2 * 512 + lane * 8);                             \
    short8 b1m = lds8(tb_ + 3 * 512 + lane * 8);                             \
    short8 b2h = lds8(tb_ + 4 * 512 + lane * 8);                             \
    short8 b2m = lds8(tb_ + 5 * 512 + lane * 8);                             \
    short8 b3h = lds8(tb_ + 6 * 512 + lane * 8);                             \
    short8 b3m = lds8(tb_ + 7 * 512 + lane * 8);                             \
    short8 a0h, a0m, a0l, a1h, a1m, a1l, a2h, a2m, a2l, a3h, a3m, a3l;       \
    split3_8(X00, X01, a0h, a0m, a0l);                                       \
    split3_8(X10, X11, a1h, a1m, a1l);                                       \
    split3_8(X20, X21, a2h, a2m, a2l);                                       \
    split3_8(X30, X31, a3h, a3m, a3l);                                       \
    if ((c) + 2 < NCH) XLOADM((c) + 2); /* after splits: WAR-safe */         \
    PROD6(c00, a0h, a0m, a0l, b0h, b0m, bl0);                                \
    PROD6(c01, a0h, a0m, a0l, b1h, b1m, bl1);                                \
    PROD6(c02, a0h, a0m, a0l, b2h, b2m, bl2);                                \
    PROD6(c03, a0h, a0m, a0l, b3h, b3m, bl3);                                \
    PROD6(c10, a1h, a1m, a1l, b0h, b0m, bl0);                                \
    PROD6(c11, a1h, a1m, a1l, b1h, b1m, bl1);                                \
    PROD6(c12, a1h, a1m, a1l, b2h, b2m, bl2);                                \
    PROD6(c13, a1h, a1m, a1l, b3h, b3m, bl3);                                \
    PROD6(c20, a2h, a2m, a2l, b0h, b0m, bl0);                                \
    PROD6(c21, a2h, a2m, a2l, b1h, b1m, bl1);                                \
    PROD6(c22, a2h, a2m, a2l, b2h, b2m, bl2);                                \
    PROD6(c23, a2h, a2m, a2l, b3h, b3m, bl3);                                \
    PROD6(c30, a3h, a3m, a3l, b0h, b0m, bl0);                                \
    PROD6(c31, a3h, a3m, a3l, b1h, b1m, bl1);                                \
    PROD6(c32, a3h, a3m, a3l, b2h, b2m, bl2);                                \
    PROD6(c33, a3h, a3m, a3l, b3h, b3m, bl3);                                \
  } while (0)

  for (int c = 0; c < NCH; c += 2) {
    BODY(c, xA00, xA01, xA10, xA11, xA20, xA21, xA30, xA31, XLOADA);
    BODY(c + 1, xB00, xB01, xB10, xB11, xB20, xB21, xB30, xB31, XLOADB);
  }

  // All waves must finish READING their stage LDS before part overwrites it.
  __syncthreads();

  // Partials: part[kq][row][e], row pad 68 floats (139264 B total).
  const int pr = kg * 4;
#define PST(A, af, g)                                                      \
  part[(size_t)(kq * 64 + (af)*16 + pr + 0) * 68 + (g)*16 + lr] = A[0];    \
  part[(size_t)(kq * 64 + (af)*16 + pr + 1) * 68 + (g)*16 + lr] = A[1];    \
  part[(size_t)(kq * 64 + (af)*16 + pr + 2) * 68 + (g)*16 + lr] = A[2];    \
  part[(size_t)(kq * 64 + (af)*16 + pr + 3) * 68 + (g)*16 + lr] = A[3];
  PST(c00, 0, 0) PST(c01, 0, 1) PST(c02, 0, 2) PST(c03, 0, 3)
  PST(c10, 1, 0) PST(c11, 1, 1) PST(c12, 1, 2) PST(c13, 1, 3)
  PST(c20, 2, 0) PST(c21, 2, 1) PST(c22, 2, 2) PST(c23, 2, 3)
  PST(c30, 3, 0) PST(c31, 3, 1) PST(c32, 3, 2) PST(c33, 3, 3)
  __syncthreads();

  // Epilogue: 8 threads/row, 8 experts each; ordered 8-way kq tree,
  // stable top-2 scan, shfl_xor merge (d=1,2,4), softmax, scatter.
  const int r = tid >> 3;
  const int eb = (tid & 7) * 8;
  const int n = rowBase + r;

  float v8[8];
#pragma unroll
  for (int j = 0; j < 8; ++j) {
    int e = eb + j;
    float s01 = part[(size_t)(0 * 64 + r) * 68 + e] +
                part[(size_t)(1 * 64 + r) * 68 + e];
    float s23 = part[(size_t)(2 * 64 + r) * 68 + e] +
                part[(size_t)(3 * 64 + r) * 68 + e];
    float s45 = part[(size_t)(4 * 64 + r) * 68 + e] +
                part[(size_t)(5 * 64 + r) * 68 + e];
    float s67 = part[(size_t)(6 * 64 + r) * 68 + e] +
                part[(size_t)(7 * 64 + r) * 68 + e];
    v8[j] = ((s01 + s23) + (s45 + s67)) + bias[e];
  }

  float av = -INFINITY, bv = -INFINITY;
  int ai = E_EXPERTS, bi = E_EXPERTS;
#pragma unroll
  for (int j = 0; j < 8; ++j) {
    int e = eb + j;
    float v = v8[j];
    bool beats_a = (v > av) || (v == av && e < ai);
    bool beats_b = (v > bv) || (v == bv && e < bi);
    if (beats_a) {
      bv = av; bi = ai; av = v; ai = e;
    } else if (beats_b) {
      bv = v; bi = e;
    }
  }
#pragma unroll
  for (int d = 1; d < 8; d <<= 1) {
    float av2 = __shfl_xor(av, d);
    float bv2 = __shfl_xor(bv, d);
    int ai2 = __shfl_xor(ai, d);
    int bi2 = __shfl_xor(bi, d);
    bool afirst = (av > av2) || (av == av2 && ai < ai2);
    float na, nb;
    int nai, nbi;
    if (afirst) {
      na = av; nai = ai;
      bool t = (bv > av2) || (bv == av2 && bi < ai2);
      nb = t ? bv : av2;
      nbi = t ? bi : ai2;
    } else {
      na = av2; nai = ai2;
      bool t = (av > bv2) || (av == bv2 && ai < bi2);
      nb = t ? av : bv2;
      nbi = t ? ai : bi2;
    }
    av = na; ai = nai; bv = nb; bi = nbi;
  }

  float e1 = expf(bv - av);
  float denom = 1.0f + e1;
  float p0 = 1.0f / denom;
  float p1 = e1 / denom;

#pragma unroll
  for (int i = 0; i < 2; ++i) {
    float4 o4;
    float* po = &o4.x;
#pragma unroll
    for (int j = 0; j < 4; ++j) {
      int e = eb + i * 4 + j;
      po[j] = (e == ai) ? p0 : (e == bi) ? p1 : 0.0f;
    }
    *reinterpret_cast<float4*>(&out_final[(size_t)n * E_EXPERTS + eb + i * 4]) =
        o4;
  }
  if ((tid & 7) == 0) {
    out_idx[(size_t)n * 2 + 0] = (float)ai;
    out_idx[(size_t)n * 2 + 1] = (float)bi;
  }
}

extern "C" void kernel_launch(void* const* d_in, const int* in_sizes, int n_in,
                              void* d_out, int out_size, void* d_ws,
                              size_t ws_size, hipStream_t stream) {
  const float* x = (const float*)d_in[0];
  const float* w = (const float*)d_in[1];
  const float* bias = (const float*)d_in[2];
  const int N = in_sizes[0] / H_DIM;  // 16384
  float* out_final = (float*)d_out;
  float* out_idx = out_final + (size_t)N * E_EXPERTS;

  unsigned short* wh = (unsigned short*)d_ws;  // h | m | l contiguous
  unsigned short* wm = wh + W_ELEMS;
  unsigned short* wl = wm + W_ELEMS;

  split_w_kernel<<<W_ELEMS / (256 * 4), 256, 0, stream>>>(w, wh, wm, wl);
  topk_router_mfma<<<N / ROWS_B, BLOCK, 0, stream>>>(x, wh, bias, out_final,
                                                     out_idx);
}